// Round 3
// baseline (238.980 us; speedup 1.0000x reference)
//
#include <hip/hip_runtime.h>

typedef __bf16 bf16x8 __attribute__((ext_vector_type(8)));
typedef float f32x4 __attribute__((ext_vector_type(4)));

#define DIM 1024
#define NSEQ 2048

// async 16B global -> LDS DMA (lane-linear: wave-uniform LDS base + lane*16)
#define GL2LDS(g, l) __builtin_amdgcn_global_load_lds( \
    (const __attribute__((address_space(1))) void*)(g), \
    (__attribute__((address_space(3))) void*)(l), 16, 0, 0)

#define MFMA16(a, b, c) __builtin_amdgcn_mfma_f32_16x16x32_bf16(a, b, c, 0, 0, 0)

// ---------------- fp32 -> bf16 weight conversion (single weight) ----------------
__global__ __launch_bounds__(256) void cvt_kernel(const float* __restrict__ s,
                                                  __bf16* __restrict__ d) {
    int i = (blockIdx.x * 256 + threadIdx.x) * 4;
    float4 f = *(const float4*)(s + i);
    union { uint2 u; __bf16 h[4]; } p;
    p.h[0] = (__bf16)f.x; p.h[1] = (__bf16)f.y;
    p.h[2] = (__bf16)f.z; p.h[3] = (__bf16)f.w;
    *(uint2*)(d + i) = p.u;
}

// ---------------- fused: convert wq/wk/wv + zero the 8 work-queue counters -----
__global__ __launch_bounds__(256) void cvt3_kernel(const float* __restrict__ wq,
                                                   const float* __restrict__ wk,
                                                   const float* __restrict__ wv,
                                                   __bf16* __restrict__ dq,
                                                   __bf16* __restrict__ dk,
                                                   __bf16* __restrict__ dv,
                                                   int* __restrict__ counters) {
    if (blockIdx.x == 0 && blockIdx.y == 0 && threadIdx.x < 8)
        counters[threadIdx.x] = 0;
    const float* s = blockIdx.y == 0 ? wq : (blockIdx.y == 1 ? wk : wv);
    __bf16*      d = blockIdx.y == 0 ? dq : (blockIdx.y == 1 ? dk : dv);
    int i = (blockIdx.x * 256 + threadIdx.x) * 4;
    float4 f = *(const float4*)(s + i);
    union { uint2 u; __bf16 h[4]; } p;
    p.h[0] = (__bf16)f.x; p.h[1] = (__bf16)f.y;
    p.h[2] = (__bf16)f.z; p.h[3] = (__bf16)f.w;
    *(uint2*)(d + i) = p.u;
}

// ---------------- RMSNorm: fp32 in, bf16 out ----------------
__global__ __launch_bounds__(256) void rmsnorm_kernel(const float* __restrict__ x,
                                                      const float* __restrict__ g,
                                                      __bf16* __restrict__ o) {
    int row = blockIdx.x;
    int t = threadIdx.x;
    float4 xv = ((const float4*)(x + (size_t)row * DIM))[t];
    float ss = xv.x*xv.x + xv.y*xv.y + xv.z*xv.z + xv.w*xv.w;
    #pragma unroll
    for (int off = 32; off; off >>= 1) ss += __shfl_xor(ss, off, 64);
    __shared__ float red[4];
    if ((t & 63) == 0) red[t >> 6] = ss;
    __syncthreads();
    ss = red[0] + red[1] + red[2] + red[3];
    float r = rsqrtf(ss * (1.0f / 1024.0f) + 1.1920929e-07f);
    float4 gv = ((const float4*)g)[t];
    union { uint2 u; __bf16 h[4]; } p;
    p.h[0] = (__bf16)(xv.x * r * gv.x);
    p.h[1] = (__bf16)(xv.y * r * gv.y);
    p.h[2] = (__bf16)(xv.z * r * gv.z);
    p.h[3] = (__bf16)(xv.w * r * gv.w);
    *(uint2*)(o + (size_t)row * DIM + t * 4) = p.u;
}

// ---------------- RoPE in-place on q AND k (4096 x 1024 bf16 each) -------------
__global__ __launch_bounds__(256) void rope_kernel(__bf16* __restrict__ qb,
                                                   __bf16* __restrict__ kb) {
    int bid = blockIdx.x;
    __bf16* x = (bid & 1) ? kb : qb;
    int gid = (bid >> 1) * 256 + threadIdx.x;   // one pair per thread
    int row = gid >> 9;          // 512 pairs per row
    int pr = gid & 511;
    int pos = row & (NSEQ - 1);
    int dp = pr & 31;            // pair index within head
    float inv = __expf(-(float)dp * (9.210340371976184f / 32.0f)); // 10000^(-2dp/64)
    float ang = (float)pos * inv;
    float sn, cs;
    sincosf(ang, &sn, &cs);
    size_t off = (size_t)row * DIM + pr * 2;
    union { unsigned int u; __bf16 h[2]; } p;
    p.u = *(const unsigned int*)(x + off);
    float x1 = (float)p.h[0], x2 = (float)p.h[1];
    p.h[0] = (__bf16)(x1 * cs - x2 * sn);
    p.h[1] = (__bf16)(x2 * cs + x1 * sn);
    *(unsigned int*)(x + off) = p.u;
}

// ---------------- shared GEMM body (unchanged) ----------------
template <typename CT>
__device__ __forceinline__ void gemm_body(const __bf16* __restrict__ A,
                                          const __bf16* __restrict__ B,
                                          CT* __restrict__ C,
                                          int mb, int nb, int ldc, float scale,
                                          __bf16* As, __bf16* Bs) {
    int t = threadIdx.x;
    int w = t >> 6, l = t & 63;
    int wm = (w >> 1) * 64, wn = (w & 1) * 64;   // wave 2x2 grid, each 64x64
    int lrow = l & 15, lq = l >> 4;
    f32x4 acc[4][4] = {};

    int srow = w * 32 + (l >> 3);
    int sc8 = (l & 7) * 8;
    const __bf16* gA = A + (size_t)(mb * 128 + srow) * 1024 + sc8;
    const __bf16* gB = B + (size_t)(nb * 128 + srow) * 1024 + sc8;
    __bf16* lA = As + (size_t)(w * 32) * 64;     // + c*8*64
    __bf16* lB = Bs + (size_t)(w * 32) * 64;

    for (int kt = 0; kt < 16; ++kt) {
        int k0 = kt * 64;
        #pragma unroll
        for (int c = 0; c < 4; ++c) {
            GL2LDS(gA + (size_t)c * 8 * 1024 + k0, lA + c * 8 * 64);
            GL2LDS(gB + (size_t)c * 8 * 1024 + k0, lB + c * 8 * 64);
        }
        __syncthreads();    // drains DMA, publishes tile
        #pragma unroll
        for (int ch = 0; ch < 2; ++ch) {
            bf16x8 af[4], bfr[4];
            #pragma unroll
            for (int i = 0; i < 4; ++i)
                af[i] = *(const bf16x8*)&As[(wm + i * 16 + lrow) * 64 + ch * 32 + lq * 8];
            #pragma unroll
            for (int i = 0; i < 4; ++i)
                bfr[i] = *(const bf16x8*)&Bs[(wn + i * 16 + lrow) * 64 + ch * 32 + lq * 8];
            #pragma unroll
            for (int rt = 0; rt < 4; ++rt)
                #pragma unroll
                for (int ct = 0; ct < 4; ++ct)
                    acc[rt][ct] = MFMA16(af[rt], bfr[ct], acc[rt][ct]);
        }
        __syncthreads();
    }
    #pragma unroll
    for (int rt = 0; rt < 4; ++rt)
        #pragma unroll
        for (int ct = 0; ct < 4; ++ct)
            #pragma unroll
            for (int r = 0; r < 4; ++r) {
                int row = mb * 128 + wm + rt * 16 + lq * 4 + r;   // C-layout
                int col = nb * 128 + wn + ct * 16 + lrow;
                C[(size_t)row * ldc + col] = (CT)(acc[rt][ct][r] * scale);
            }
}

// Fused QKV projections: grid (32, 8, 3) -> 768 blocks = 3 blocks/CU.
// Q scale folds BOTH 1/sqrt(64) AND log2(e): softmax runs in the exp2 domain.
__global__ __launch_bounds__(256) void qkv_kernel(const __bf16* __restrict__ x,
                                                  const __bf16* __restrict__ wq,
                                                  const __bf16* __restrict__ wk,
                                                  const __bf16* __restrict__ wv,
                                                  __bf16* __restrict__ qb,
                                                  __bf16* __restrict__ kb,
                                                  __bf16* __restrict__ vtb) {
    __shared__ __bf16 As[128 * 64];
    __shared__ __bf16 Bs[128 * 64];
    int bm = blockIdx.x, bn = blockIdx.y, z = blockIdx.z;
    if (z == 0)      gemm_body<__bf16>(x,  wq, qb,  bm, bn, 1024,
                                       0.125f * 1.44269504088896340736f, As, Bs);
    else if (z == 1) gemm_body<__bf16>(x,  wk, kb,  bm, bn, 1024, 1.0f,   As, Bs);
    else             gemm_body<__bf16>(wv, x,  vtb, bn, bm, 4096, 1.0f,   As, Bs);
}

// Output projection: all-bf16 DMA path, fp32 store.
__global__ __launch_bounds__(256) void wo_kernel(const __bf16* __restrict__ A,
                                                 const __bf16* __restrict__ B,
                                                 float* __restrict__ C) {
    __shared__ __bf16 As[128 * 64];
    __shared__ __bf16 Bs[128 * 64];
    gemm_body<float>(A, B, C, blockIdx.x, blockIdx.y, 1024, 1.0f, As, Bs);
}

// ---------------- Causal flash attention v3: barrier-free wave-workers ----------
// R2 post-mortem: LDS pipe was ~74% busy (72 b128 reads/block-iter + staging +
// 350cy conflicts) -> LDS-throughput-bound. Per-XCD K/V working set = 4 bh x
// 512KB = 2MB <= 4MB L2, so drop ALL K/V LDS staging (m169 lesson): read K/V
// MFMA fragments directly from global (L2-served), one-tile register prefetch
// (16KB/wave in flight covers L2 latency). Each WAVE is an independent worker
// owning 32 q-rows (2 x 16-row MFMA groups -> K/V bytes serve 2x the work).
// No __syncthreads anywhere. Items: (bh, 32-row q-tile) = 2048, long-first per
// XCD; 1024 wave-workers (256 blocks) -> greedy LPT pairs 32+1, 31+2, ...
// = exactly 33 k-iters per worker, near-zero tail.
__global__ __launch_bounds__(256) void attn_kernel(const __bf16* __restrict__ q,
                                                   const __bf16* __restrict__ kk,
                                                   const __bf16* __restrict__ vt,
                                                   __bf16* __restrict__ o,
                                                   int* __restrict__ counters) {
    int xcd = blockIdx.x & 7;            // dispatch round-robins over XCDs
    int t = threadIdx.x;
    int w = t >> 6, l = t & 63;
    int lrow = l & 15, lq = l >> 4;

    __shared__ __bf16 Ps[4][32 * 76];    // per-wave P^T strip [qrow][key], stride 76
    __bf16* pw = Ps[w];

    for (;;) {
        int it = 0;
        if (l == 0) it = atomicAdd(&counters[xcd], 1);
        it = __shfl(it, 0, 64);
        if (it >= 256) break;            // 256 items per XCD
        int qq = 63 - (it >> 2);         // 32-row q-tile index, long-first (LPT)
        int bh = xcd * 4 + (it & 3);     // 4 (b,h) pairs resident per XCD (L2)
        int h = bh & 15;
        int b = bh >> 4;
        int rowbase = b * NSEQ;
        int JT = qq >> 1;                // last 64-key tile index

        const __bf16* kbase = kk + (size_t)rowbase * DIM + h * 64;
        const __bf16* vbase = vt + (size_t)(h * 64) * 4096 + b * 2048;

        // Q fragments: 2 groups of 16 qrows; B[n=qrow=lrow][k=d=lq*8+j]
        bf16x8 qf[2][2];
        #pragma unroll
        for (int g = 0; g < 2; ++g) {
            const __bf16* qp = q + (size_t)(rowbase + qq * 32 + g * 16 + lrow) * DIM + h * 64;
            qf[g][0] = *(const bf16x8*)(qp + lq * 8);
            qf[g][1] = *(const bf16x8*)(qp + 32 + lq * 8);
        }

        f32x4 oacc[2][4] = {};           // O^T per group: [d-chunk], col = qrow
        float m_r[2] = {-1e30f, -1e30f};
        float l_r[2] = {0.0f, 0.0f};

        // K/V fragment registers, ping-pong. A(K)[m=key=ct*16+lrow][k=d],
        // A(V^T)[m=d=ct*16+lrow][k=key]; 8 x 16B loads each.
        bf16x8 kA[8], kB[8], vA[8], vB[8];
        #pragma unroll
        for (int ct = 0; ct < 4; ++ct) {
            const __bf16* kp = kbase + (size_t)(ct * 16 + lrow) * DIM;
            kA[ct * 2]     = *(const bf16x8*)(kp + lq * 8);
            kA[ct * 2 + 1] = *(const bf16x8*)(kp + 32 + lq * 8);
            const __bf16* vp = vbase + (size_t)(ct * 16 + lrow) * 4096;
            vA[ct * 2]     = *(const bf16x8*)(vp + lq * 8);
            vA[ct * 2 + 1] = *(const bf16x8*)(vp + 32 + lq * 8);
        }

        auto trip = [&](bf16x8 (&kc)[8], bf16x8 (&kn)[8],
                        bf16x8 (&vc)[8], bf16x8 (&vn)[8], int jt) {
            // QK^T for both q-row groups (waits on kc loads)
            f32x4 st[2][4];
            #pragma unroll
            for (int ct = 0; ct < 4; ++ct)
                #pragma unroll
                for (int g = 0; g < 2; ++g) {
                    f32x4 z = {};
                    z = MFMA16(kc[ct * 2],     qf[g][0], z);
                    z = MFMA16(kc[ct * 2 + 1], qf[g][1], z);
                    st[g][ct] = z;   // key = ct*16+lq*4+r, qrow(local) = lrow
                }
            // prefetch next K/V tile early: full softmax+PV phase covers latency
            if (jt < JT) {
                int j1 = (jt + 1) * 64;
                #pragma unroll
                for (int ct = 0; ct < 4; ++ct) {
                    const __bf16* kp = kbase + (size_t)(j1 + ct * 16 + lrow) * DIM;
                    kn[ct * 2]     = *(const bf16x8*)(kp + lq * 8);
                    kn[ct * 2 + 1] = *(const bf16x8*)(kp + 32 + lq * 8);
                    const __bf16* vp = vbase + (size_t)(ct * 16 + lrow) * 4096 + j1;
                    vn[ct * 2]     = *(const bf16x8*)(vp + lq * 8);
                    vn[ct * 2 + 1] = *(const bf16x8*)(vp + 32 + lq * 8);
                }
            }
            if (jt == JT) {              // causal mask, per group
                #pragma unroll
                for (int g = 0; g < 2; ++g) {
                    int qr = qq * 32 + g * 16 + lrow - JT * 64;
                    #pragma unroll
                    for (int ct = 0; ct < 4; ++ct)
                        #pragma unroll
                        for (int r = 0; r < 4; ++r)
                            if (ct * 16 + lq * 4 + r > qr) st[g][ct][r] = -3.0e38f;
                }
            }
            // online softmax (exp2 domain) per group; 2+2 shuffles each
            #pragma unroll
            for (int g = 0; g < 2; ++g) {
                float m0 = fmaxf(fmaxf(st[g][0][0], st[g][0][1]), fmaxf(st[g][0][2], st[g][0][3]));
                float m1 = fmaxf(fmaxf(st[g][1][0], st[g][1][1]), fmaxf(st[g][1][2], st[g][1][3]));
                float m2 = fmaxf(fmaxf(st[g][2][0], st[g][2][1]), fmaxf(st[g][2][2], st[g][2][3]));
                float m3 = fmaxf(fmaxf(st[g][3][0], st[g][3][1]), fmaxf(st[g][3][2], st[g][3][3]));
                float mx = fmaxf(fmaxf(m0, m1), fmaxf(m2, m3));
                mx = fmaxf(mx, __shfl_xor(mx, 16, 64));
                mx = fmaxf(mx, __shfl_xor(mx, 32, 64));
                // defer-max (T13): P bounded by 2^8; f32 accum tolerates
                if (!__all(mx - m_r[g] <= 8.0f)) {
                    float mnew = fmaxf(m_r[g], mx);
                    float alpha = __builtin_amdgcn_exp2f(m_r[g] - mnew);
                    l_r[g] *= alpha;
                    #pragma unroll
                    for (int ct = 0; ct < 4; ++ct)
                        #pragma unroll
                        for (int r = 0; r < 4; ++r) oacc[g][ct][r] *= alpha;
                    m_r[g] = mnew;
                }
                float ps = 0.0f;
                #pragma unroll
                for (int ct = 0; ct < 4; ++ct)
                    #pragma unroll
                    for (int r = 0; r < 4; ++r) {
                        float p = __builtin_amdgcn_exp2f(st[g][ct][r] - m_r[g]);
                        st[g][ct][r] = p;
                        ps += p;
                    }
                ps += __shfl_xor(ps, 16, 64);
                ps += __shfl_xor(ps, 32, 64);
                l_r[g] += ps;
            }
            // P^T -> per-wave LDS strip (same-wave reuse: lgkmcnt only, no barrier)
            #pragma unroll
            for (int g = 0; g < 2; ++g)
                #pragma unroll
                for (int ct = 0; ct < 4; ++ct) {
                    union { uint2 u; __bf16 h4[4]; } pk;
                    #pragma unroll
                    for (int r = 0; r < 4; ++r) pk.h4[r] = (__bf16)st[g][ct][r];
                    *(uint2*)&pw[(g * 16 + lrow) * 76 + ct * 16 + lq * 4] = pk.u;
                }
            bf16x8 pb[2][2];
            #pragma unroll
            for (int g = 0; g < 2; ++g) {
                pb[g][0] = *(const bf16x8*)&pw[(g * 16 + lrow) * 76 + lq * 8];
                pb[g][1] = *(const bf16x8*)&pw[(g * 16 + lrow) * 76 + 32 + lq * 8];
            }
            // O^T += V^T * P^T (waits on vc loads)
            #pragma unroll
            for (int ct = 0; ct < 4; ++ct)
                #pragma unroll
                for (int g = 0; g < 2; ++g) {
                    oacc[g][ct] = MFMA16(vc[ct * 2],     pb[g][0], oacc[g][ct]);
                    oacc[g][ct] = MFMA16(vc[ct * 2 + 1], pb[g][1], oacc[g][ct]);
                }
        };

        int jt = 0;
        for (;;) {
            trip(kA, kB, vA, vB, jt);
            if (jt == JT) break;
            ++jt;
            trip(kB, kA, vB, vA, jt);
            if (jt == JT) break;
            ++jt;
        }

        // epilogue: O^T C-layout -> o[qrow][d], per group
        #pragma unroll
        for (int g = 0; g < 2; ++g) {
            float rcp = 1.0f / l_r[g];
            const size_t orow = (size_t)(rowbase + qq * 32 + g * 16 + lrow) * DIM + h * 64;
            #pragma unroll
            for (int ct = 0; ct < 4; ++ct) {
                union { uint2 u; __bf16 h4[4]; } pk;
                #pragma unroll
                for (int r = 0; r < 4; ++r) pk.h4[r] = (__bf16)(oacc[g][ct][r] * rcp);
                *(uint2*)(o + orow + ct * 16 + lq * 4) = pk.u;
            }
        }
    }
}

extern "C" void kernel_launch(void* const* d_in, const int* in_sizes, int n_in,
                              void* d_out, int out_size, void* d_ws, size_t ws_size,
                              hipStream_t stream) {
    const float* tokens = (const float*)d_in[0];
    const float* gamma  = (const float*)d_in[1];
    const float* wq = (const float*)d_in[2];
    const float* wk = (const float*)d_in[3];
    const float* wv = (const float*)d_in[4];
    const float* wo = (const float*)d_in[5];

    __bf16* ws  = (__bf16*)d_ws;
    __bf16* x   = ws;                           // 4096*1024
    __bf16* qb  = x   + (size_t)4096 * 1024;
    __bf16* kb  = qb  + (size_t)4096 * 1024;
    __bf16* vtb = kb  + (size_t)4096 * 1024;    // V^T: 1024 x 4096
    __bf16* ao  = x;                            // alias: attn out reuses x's buffer
    __bf16* wob = qb;                           // alias: qb dead after attn
    float*  out = (float*)d_out;

    // bf16 Q/K/V weights stashed in d_out (consumed by qkv before wo overwrites);
    // work-queue counters at d_out+8MB (written after qkv, dead before wo's C).
    __bf16* wqb = (__bf16*)d_out;
    __bf16* wkb = wqb + (size_t)1024 * 1024;
    __bf16* wvb = wkb + (size_t)1024 * 1024;
    int* counters = (int*)((char*)d_out + (size_t)8 * 1024 * 1024);

    cvt3_kernel<<<dim3(1024, 3), 256, 0, stream>>>(wq, wk, wv, wqb, wkb, wvb, counters);

    rmsnorm_kernel<<<4096, 256, 0, stream>>>(tokens, gamma, x);

    qkv_kernel<<<dim3(32, 8, 3), 256, 0, stream>>>(x, wqb, wkb, wvb, qb, kb, vtb);

    rope_kernel<<<16384, 256, 0, stream>>>(qb, kb);

    attn_kernel<<<256, 256, 0, stream>>>(qb, kb, vtb, ao, counters);

    cvt_kernel<<<1024, 256, 0, stream>>>(wo, wob);   // qb region is dead now

    wo_kernel<<<dim3(32, 8), 256, 0, stream>>>(ao, wob, out);
}

// Round 4
// 234.509 us; speedup vs baseline: 1.0191x; 1.0191x over previous
//
#include <hip/hip_runtime.h>

typedef __bf16 bf16x8 __attribute__((ext_vector_type(8)));
typedef float f32x4 __attribute__((ext_vector_type(4)));

#define DIM 1024
#define NSEQ 2048

// async 16B global -> LDS DMA (lane-linear: wave-uniform LDS base + lane*16)
#define GL2LDS(g, l) __builtin_amdgcn_global_load_lds( \
    (const __attribute__((address_space(1))) void*)(g), \
    (__attribute__((address_space(3))) void*)(l), 16, 0, 0)

#define MFMA16(a, b, c) __builtin_amdgcn_mfma_f32_16x16x32_bf16(a, b, c, 0, 0, 0)

// ---------------- fp32 -> bf16 weight conversion (single weight) ----------------
__global__ __launch_bounds__(256) void cvt_kernel(const float* __restrict__ s,
                                                  __bf16* __restrict__ d) {
    int i = (blockIdx.x * 256 + threadIdx.x) * 4;
    float4 f = *(const float4*)(s + i);
    union { uint2 u; __bf16 h[4]; } p;
    p.h[0] = (__bf16)f.x; p.h[1] = (__bf16)f.y;
    p.h[2] = (__bf16)f.z; p.h[3] = (__bf16)f.w;
    *(uint2*)(d + i) = p.u;
}

// ---------------- fused: convert wq/wk/wv + zero the 8 work-queue counters -----
__global__ __launch_bounds__(256) void cvt3_kernel(const float* __restrict__ wq,
                                                   const float* __restrict__ wk,
                                                   const float* __restrict__ wv,
                                                   __bf16* __restrict__ dq,
                                                   __bf16* __restrict__ dk,
                                                   __bf16* __restrict__ dv,
                                                   int* __restrict__ counters) {
    if (blockIdx.x == 0 && blockIdx.y == 0 && threadIdx.x < 8)
        counters[threadIdx.x] = 0;
    const float* s = blockIdx.y == 0 ? wq : (blockIdx.y == 1 ? wk : wv);
    __bf16*      d = blockIdx.y == 0 ? dq : (blockIdx.y == 1 ? dk : dv);
    int i = (blockIdx.x * 256 + threadIdx.x) * 4;
    float4 f = *(const float4*)(s + i);
    union { uint2 u; __bf16 h[4]; } p;
    p.h[0] = (__bf16)f.x; p.h[1] = (__bf16)f.y;
    p.h[2] = (__bf16)f.z; p.h[3] = (__bf16)f.w;
    *(uint2*)(d + i) = p.u;
}

// ---------------- RMSNorm: fp32 in, bf16 out ----------------
__global__ __launch_bounds__(256) void rmsnorm_kernel(const float* __restrict__ x,
                                                      const float* __restrict__ g,
                                                      __bf16* __restrict__ o) {
    int row = blockIdx.x;
    int t = threadIdx.x;
    float4 xv = ((const float4*)(x + (size_t)row * DIM))[t];
    float ss = xv.x*xv.x + xv.y*xv.y + xv.z*xv.z + xv.w*xv.w;
    #pragma unroll
    for (int off = 32; off; off >>= 1) ss += __shfl_xor(ss, off, 64);
    __shared__ float red[4];
    if ((t & 63) == 0) red[t >> 6] = ss;
    __syncthreads();
    ss = red[0] + red[1] + red[2] + red[3];
    float r = rsqrtf(ss * (1.0f / 1024.0f) + 1.1920929e-07f);
    float4 gv = ((const float4*)g)[t];
    union { uint2 u; __bf16 h[4]; } p;
    p.h[0] = (__bf16)(xv.x * r * gv.x);
    p.h[1] = (__bf16)(xv.y * r * gv.y);
    p.h[2] = (__bf16)(xv.z * r * gv.z);
    p.h[3] = (__bf16)(xv.w * r * gv.w);
    *(uint2*)(o + (size_t)row * DIM + t * 4) = p.u;
}

// ---------------- RoPE in-place on q AND k (4096 x 1024 bf16 each) -------------
__global__ __launch_bounds__(256) void rope_kernel(__bf16* __restrict__ qb,
                                                   __bf16* __restrict__ kb) {
    int bid = blockIdx.x;
    __bf16* x = (bid & 1) ? kb : qb;
    int gid = (bid >> 1) * 256 + threadIdx.x;   // one pair per thread
    int row = gid >> 9;          // 512 pairs per row
    int pr = gid & 511;
    int pos = row & (NSEQ - 1);
    int dp = pr & 31;            // pair index within head
    float inv = __expf(-(float)dp * (9.210340371976184f / 32.0f)); // 10000^(-2dp/64)
    float ang = (float)pos * inv;
    float sn, cs;
    sincosf(ang, &sn, &cs);
    size_t off = (size_t)row * DIM + pr * 2;
    union { unsigned int u; __bf16 h[2]; } p;
    p.u = *(const unsigned int*)(x + off);
    float x1 = (float)p.h[0], x2 = (float)p.h[1];
    p.h[0] = (__bf16)(x1 * cs - x2 * sn);
    p.h[1] = (__bf16)(x2 * cs + x1 * sn);
    *(unsigned int*)(x + off) = p.u;
}

// ---------------- shared GEMM body (unchanged) ----------------
template <typename CT>
__device__ __forceinline__ void gemm_body(const __bf16* __restrict__ A,
                                          const __bf16* __restrict__ B,
                                          CT* __restrict__ C,
                                          int mb, int nb, int ldc, float scale,
                                          __bf16* As, __bf16* Bs) {
    int t = threadIdx.x;
    int w = t >> 6, l = t & 63;
    int wm = (w >> 1) * 64, wn = (w & 1) * 64;   // wave 2x2 grid, each 64x64
    int lrow = l & 15, lq = l >> 4;
    f32x4 acc[4][4] = {};

    int srow = w * 32 + (l >> 3);
    int sc8 = (l & 7) * 8;
    const __bf16* gA = A + (size_t)(mb * 128 + srow) * 1024 + sc8;
    const __bf16* gB = B + (size_t)(nb * 128 + srow) * 1024 + sc8;
    __bf16* lA = As + (size_t)(w * 32) * 64;     // + c*8*64
    __bf16* lB = Bs + (size_t)(w * 32) * 64;

    for (int kt = 0; kt < 16; ++kt) {
        int k0 = kt * 64;
        #pragma unroll
        for (int c = 0; c < 4; ++c) {
            GL2LDS(gA + (size_t)c * 8 * 1024 + k0, lA + c * 8 * 64);
            GL2LDS(gB + (size_t)c * 8 * 1024 + k0, lB + c * 8 * 64);
        }
        __syncthreads();    // drains DMA, publishes tile
        #pragma unroll
        for (int ch = 0; ch < 2; ++ch) {
            bf16x8 af[4], bfr[4];
            #pragma unroll
            for (int i = 0; i < 4; ++i)
                af[i] = *(const bf16x8*)&As[(wm + i * 16 + lrow) * 64 + ch * 32 + lq * 8];
            #pragma unroll
            for (int i = 0; i < 4; ++i)
                bfr[i] = *(const bf16x8*)&Bs[(wn + i * 16 + lrow) * 64 + ch * 32 + lq * 8];
            #pragma unroll
            for (int rt = 0; rt < 4; ++rt)
                #pragma unroll
                for (int ct = 0; ct < 4; ++ct)
                    acc[rt][ct] = MFMA16(af[rt], bfr[ct], acc[rt][ct]);
        }
        __syncthreads();
    }
    #pragma unroll
    for (int rt = 0; rt < 4; ++rt)
        #pragma unroll
        for (int ct = 0; ct < 4; ++ct)
            #pragma unroll
            for (int r = 0; r < 4; ++r) {
                int row = mb * 128 + wm + rt * 16 + lq * 4 + r;   // C-layout
                int col = nb * 128 + wn + ct * 16 + lrow;
                C[(size_t)row * ldc + col] = (CT)(acc[rt][ct][r] * scale);
            }
}

// Fused QKV projections: grid (32, 8, 3) -> 768 blocks = 3 blocks/CU.
// Q scale folds BOTH 1/sqrt(64) AND log2(e): softmax runs in the exp2 domain.
__global__ __launch_bounds__(256) void qkv_kernel(const __bf16* __restrict__ x,
                                                  const __bf16* __restrict__ wq,
                                                  const __bf16* __restrict__ wk,
                                                  const __bf16* __restrict__ wv,
                                                  __bf16* __restrict__ qb,
                                                  __bf16* __restrict__ kb,
                                                  __bf16* __restrict__ vtb) {
    __shared__ __bf16 As[128 * 64];
    __shared__ __bf16 Bs[128 * 64];
    int bm = blockIdx.x, bn = blockIdx.y, z = blockIdx.z;
    if (z == 0)      gemm_body<__bf16>(x,  wq, qb,  bm, bn, 1024,
                                       0.125f * 1.44269504088896340736f, As, Bs);
    else if (z == 1) gemm_body<__bf16>(x,  wk, kb,  bm, bn, 1024, 1.0f,   As, Bs);
    else             gemm_body<__bf16>(wv, x,  vtb, bn, bm, 4096, 1.0f,   As, Bs);
}

// Output projection: all-bf16 DMA path, fp32 store.
__global__ __launch_bounds__(256) void wo_kernel(const __bf16* __restrict__ A,
                                                 const __bf16* __restrict__ B,
                                                 float* __restrict__ C) {
    __shared__ __bf16 As[128 * 64];
    __shared__ __bf16 Bs[128 * 64];
    gemm_body<float>(A, B, C, blockIdx.x, blockIdx.y, 1024, 1.0f, As, Bs);
}

// ---------------- Causal flash attention v4: LDS-staged, 32 q-rows per wave -----
// R3 post-mortem: global-gather K/V is latency-bound (89us). Back to R2's LDS
// staging, but AMORTIZE the LDS pipe (the R2 bottleneck, ~74% busy): each wave
// computes TWO 16-row MFMA groups (32 q-rows), reusing every K/V LDS fragment
// across both -> LDS cycles per unit work halved, MFMA per iter doubled.
// Block = 4 waves = 128 q-rows. Item = (bh, 128-row q-tile): 64 per XCD, iters
// 2..32. Grid = 256 blocks (1 worker/CU); per-XCD LPT queue pairs 32+2, 30+4,
// ... 18+16 -> every worker exactly 34 iters (near-perfect balance). K/V
// double-buffered, reg-staged (stride-72 LDS), ONE barrier per iteration.
__global__ __launch_bounds__(256) void attn_kernel(const __bf16* __restrict__ q,
                                                   const __bf16* __restrict__ kk,
                                                   const __bf16* __restrict__ vt,
                                                   __bf16* __restrict__ o,
                                                   int* __restrict__ counters) {
    int xcd = blockIdx.x & 7;            // dispatch round-robins over XCDs
    int t = threadIdx.x;
    int w = t >> 6, l = t & 63;
    int lrow = l & 15, lq = l >> 4;
    int row0 = t >> 3;
    int c8 = (t & 7) * 8;

    __shared__ __bf16 Kt[2][64 * 72];    // [key][d], stride 72
    __shared__ __bf16 Vs[2][64 * 72];    // [d][key], stride 72 (from vt)
    __shared__ __bf16 Ps[4][32 * 76];    // per-wave P^T strip [qrow][key], stride 76
    __shared__ int s_item;
    __bf16* pw = Ps[w];

    for (;;) {
        if (t == 0) s_item = atomicAdd(&counters[xcd], 1);
        __syncthreads();                 // broadcast item; also fences LDS reuse
        int item = s_item;
        if (item >= 64) break;           // 64 items per XCD (4 bh x 16 q-tiles)
        int qt = 15 - (item >> 2);       // 128-row q-tile, long-first (LPT)
        int bh = xcd * 4 + (item & 3);   // 4 (b,h) pairs resident per XCD (L2)
        int h = bh & 15;
        int b = bh >> 4;
        int rowbase = b * NSEQ;
        int JT = 2 * qt + 1;             // last 64-key tile index

        const __bf16* kbase = kk + (size_t)rowbase * DIM + h * 64;
        const __bf16* vbase = vt + (size_t)(h * 64) * 4096 + b * 2048;

        // Q fragments, 2 groups of 16 qrows per wave (wave covers 32 rows):
        // B[n=qrow=lrow][k=d=lq*8+j]
        bf16x8 qf[2][2];
        #pragma unroll
        for (int g = 0; g < 2; ++g) {
            const __bf16* qp = q + (size_t)(rowbase + qt * 128 + w * 32 + g * 16 + lrow) * DIM + h * 64;
            qf[g][0] = *(const bf16x8*)(qp + lq * 8);
            qf[g][1] = *(const bf16x8*)(qp + 32 + lq * 8);
        }

        f32x4 oacc[2][4] = {};           // O^T per group: [d-chunk], col = qrow
        float m_r[2] = {-1e30f, -1e30f};
        float l_r[2] = {0.0f, 0.0f};

        // stage tile 0 into buffer 0 (explicit named regs -> no scratch)
        uint4 kr0, kr1, vr0, vr1;
        kr0 = *(const uint4*)(kbase + (size_t)row0 * DIM + c8);
        kr1 = *(const uint4*)(kbase + (size_t)(row0 + 32) * DIM + c8);
        vr0 = *(const uint4*)(vbase + (size_t)row0 * 4096 + c8);
        vr1 = *(const uint4*)(vbase + (size_t)(row0 + 32) * 4096 + c8);
        *(uint4*)&Kt[0][row0 * 72 + c8] = kr0;
        *(uint4*)&Kt[0][(row0 + 32) * 72 + c8] = kr1;
        *(uint4*)&Vs[0][row0 * 72 + c8] = vr0;
        *(uint4*)&Vs[0][(row0 + 32) * 72 + c8] = vr1;
        __syncthreads();

        for (int jt = 0; jt <= JT; ++jt) {
            int cur = jt & 1;
            if (jt < JT) {               // register prefetch of next K/V tile
                int j0 = (jt + 1) * 64;
                kr0 = *(const uint4*)(kbase + (size_t)(j0 + row0) * DIM + c8);
                kr1 = *(const uint4*)(kbase + (size_t)(j0 + row0 + 32) * DIM + c8);
                vr0 = *(const uint4*)(vbase + (size_t)row0 * 4096 + j0 + c8);
                vr1 = *(const uint4*)(vbase + (size_t)(row0 + 32) * 4096 + j0 + c8);
            }
            // S^T strips for both groups: A = K[m=key][k=d], B = Q
            // K fragments read ONCE, used by both groups.
            f32x4 st[2][4];
            #pragma unroll
            for (int ct = 0; ct < 4; ++ct) {
                bf16x8 ka0 = *(const bf16x8*)&Kt[cur][(ct * 16 + lrow) * 72 + lq * 8];
                bf16x8 ka1 = *(const bf16x8*)&Kt[cur][(ct * 16 + lrow) * 72 + 32 + lq * 8];
                #pragma unroll
                for (int g = 0; g < 2; ++g) {
                    f32x4 z = {};
                    z = MFMA16(ka0, qf[g][0], z);
                    z = MFMA16(ka1, qf[g][1], z);
                    st[g][ct] = z;       // key = ct*16+lq*4+r, qrow(local) = lrow
                }
            }
            if (jt >= JT - 1) {          // causal mask (last two tiles only)
                #pragma unroll
                for (int g = 0; g < 2; ++g) {
                    int qrel = qt * 128 + w * 32 + g * 16 + lrow - jt * 64;
                    #pragma unroll
                    for (int ct = 0; ct < 4; ++ct)
                        #pragma unroll
                        for (int r = 0; r < 4; ++r)
                            if (ct * 16 + lq * 4 + r > qrel) st[g][ct][r] = -3.0e38f;
                }
            }
            // online softmax (exp2 domain) per group; 2+2 shuffles each
            #pragma unroll
            for (int g = 0; g < 2; ++g) {
                float m0 = fmaxf(fmaxf(st[g][0][0], st[g][0][1]), fmaxf(st[g][0][2], st[g][0][3]));
                float m1 = fmaxf(fmaxf(st[g][1][0], st[g][1][1]), fmaxf(st[g][1][2], st[g][1][3]));
                float m2 = fmaxf(fmaxf(st[g][2][0], st[g][2][1]), fmaxf(st[g][2][2], st[g][2][3]));
                float m3 = fmaxf(fmaxf(st[g][3][0], st[g][3][1]), fmaxf(st[g][3][2], st[g][3][3]));
                float mx = fmaxf(fmaxf(m0, m1), fmaxf(m2, m3));
                mx = fmaxf(mx, __shfl_xor(mx, 16, 64));
                mx = fmaxf(mx, __shfl_xor(mx, 32, 64));
                // defer-max (T13): P bounded by 2^8; f32 accum tolerates
                if (!__all(mx - m_r[g] <= 8.0f)) {
                    float mnew = fmaxf(m_r[g], mx);
                    float alpha = __builtin_amdgcn_exp2f(m_r[g] - mnew);
                    l_r[g] *= alpha;
                    #pragma unroll
                    for (int ct = 0; ct < 4; ++ct)
                        #pragma unroll
                        for (int r = 0; r < 4; ++r) oacc[g][ct][r] *= alpha;
                    m_r[g] = mnew;
                }
                float ps = 0.0f;
                #pragma unroll
                for (int ct = 0; ct < 4; ++ct)
                    #pragma unroll
                    for (int r = 0; r < 4; ++r) {
                        float p = __builtin_amdgcn_exp2f(st[g][ct][r] - m_r[g]);
                        st[g][ct][r] = p;
                        ps += p;
                    }
                ps += __shfl_xor(ps, 16, 64);
                ps += __shfl_xor(ps, 32, 64);
                l_r[g] += ps;
            }
            // P^T -> per-wave LDS strip (same-wave reuse, no barrier)
            #pragma unroll
            for (int g = 0; g < 2; ++g)
                #pragma unroll
                for (int ct = 0; ct < 4; ++ct) {
                    union { uint2 u; __bf16 h4[4]; } pk;
                    #pragma unroll
                    for (int r = 0; r < 4; ++r) pk.h4[r] = (__bf16)st[g][ct][r];
                    *(uint2*)&pw[(g * 16 + lrow) * 76 + ct * 16 + lq * 4] = pk.u;
                }
            bf16x8 pb[2][2];
            #pragma unroll
            for (int g = 0; g < 2; ++g) {
                pb[g][0] = *(const bf16x8*)&pw[(g * 16 + lrow) * 76 + lq * 8];
                pb[g][1] = *(const bf16x8*)&pw[(g * 16 + lrow) * 76 + 32 + lq * 8];
            }
            // O^T += V^T * P^T; V fragments read ONCE, used by both groups.
            #pragma unroll
            for (int ct = 0; ct < 4; ++ct) {
                bf16x8 va0 = *(const bf16x8*)&Vs[cur][(ct * 16 + lrow) * 72 + lq * 8];
                bf16x8 va1 = *(const bf16x8*)&Vs[cur][(ct * 16 + lrow) * 72 + 32 + lq * 8];
                #pragma unroll
                for (int g = 0; g < 2; ++g) {
                    oacc[g][ct] = MFMA16(va0, pb[g][0], oacc[g][ct]);
                    oacc[g][ct] = MFMA16(va1, pb[g][1], oacc[g][ct]);
                }
            }
            // store prefetched tile into ALTERNATE buffer; safe pre-barrier:
            // other waves in this window only read buffer `cur`.
            if (jt < JT) {
                *(uint4*)&Kt[cur ^ 1][row0 * 72 + c8] = kr0;
                *(uint4*)&Kt[cur ^ 1][(row0 + 32) * 72 + c8] = kr1;
                *(uint4*)&Vs[cur ^ 1][row0 * 72 + c8] = vr0;
                *(uint4*)&Vs[cur ^ 1][(row0 + 32) * 72 + c8] = vr1;
            }
            __syncthreads();             // single barrier per iteration
        }
        // epilogue: O^T C-layout -> o[qrow][d], per group
        #pragma unroll
        for (int g = 0; g < 2; ++g) {
            float rcp = 1.0f / l_r[g];
            const size_t orow = (size_t)(rowbase + qt * 128 + w * 32 + g * 16 + lrow) * DIM + h * 64;
            #pragma unroll
            for (int ct = 0; ct < 4; ++ct) {
                union { uint2 u; __bf16 h4[4]; } pk;
                #pragma unroll
                for (int r = 0; r < 4; ++r) pk.h4[r] = (__bf16)(oacc[g][ct][r] * rcp);
                *(uint2*)(o + orow + ct * 16 + lq * 4) = pk.u;
            }
        }
    }
}

extern "C" void kernel_launch(void* const* d_in, const int* in_sizes, int n_in,
                              void* d_out, int out_size, void* d_ws, size_t ws_size,
                              hipStream_t stream) {
    const float* tokens = (const float*)d_in[0];
    const float* gamma  = (const float*)d_in[1];
    const float* wq = (const float*)d_in[2];
    const float* wk = (const float*)d_in[3];
    const float* wv = (const float*)d_in[4];
    const float* wo = (const float*)d_in[5];

    __bf16* ws  = (__bf16*)d_ws;
    __bf16* x   = ws;                           // 4096*1024
    __bf16* qb  = x   + (size_t)4096 * 1024;
    __bf16* kb  = qb  + (size_t)4096 * 1024;
    __bf16* vtb = kb  + (size_t)4096 * 1024;    // V^T: 1024 x 4096
    __bf16* ao  = x;                            // alias: attn out reuses x's buffer
    __bf16* wob = qb;                           // alias: qb dead after attn
    float*  out = (float*)d_out;

    // bf16 Q/K/V weights stashed in d_out (consumed by qkv before wo overwrites);
    // work-queue counters at d_out+8MB (written after qkv, dead before wo's C).
    __bf16* wqb = (__bf16*)d_out;
    __bf16* wkb = wqb + (size_t)1024 * 1024;
    __bf16* wvb = wkb + (size_t)1024 * 1024;
    int* counters = (int*)((char*)d_out + (size_t)8 * 1024 * 1024);

    cvt3_kernel<<<dim3(1024, 3), 256, 0, stream>>>(wq, wk, wv, wqb, wkb, wvb, counters);

    rmsnorm_kernel<<<4096, 256, 0, stream>>>(tokens, gamma, x);

    qkv_kernel<<<dim3(32, 8, 3), 256, 0, stream>>>(x, wqb, wkb, wvb, qb, kb, vtb);

    rope_kernel<<<16384, 256, 0, stream>>>(qb, kb);

    attn_kernel<<<256, 256, 0, stream>>>(qb, kb, vtb, ao, counters);

    cvt_kernel<<<1024, 256, 0, stream>>>(wo, wob);   // qb region is dead now

    wo_kernel<<<dim3(32, 8), 256, 0, stream>>>(ao, wob, out);
}

// Round 6
// 201.777 us; speedup vs baseline: 1.1844x; 1.1622x over previous
//
#include <hip/hip_runtime.h>

typedef __bf16 bf16x8 __attribute__((ext_vector_type(8)));
typedef float f32x4 __attribute__((ext_vector_type(4)));

#define DIM 1024
#define NSEQ 2048

// async 16B global -> LDS DMA (lane-linear: wave-uniform LDS base + lane*16)
#define GL2LDS(g, l) __builtin_amdgcn_global_load_lds( \
    (const __attribute__((address_space(1))) void*)(g), \
    (__attribute__((address_space(3))) void*)(l), 16, 0, 0)

#define MFMA16(a, b, c) __builtin_amdgcn_mfma_f32_16x16x32_bf16(a, b, c, 0, 0, 0)

// ---------------- fp32 -> bf16 weight conversion (single weight) ----------------
__global__ __launch_bounds__(256) void cvt_kernel(const float* __restrict__ s,
                                                  __bf16* __restrict__ d) {
    int i = (blockIdx.x * 256 + threadIdx.x) * 4;
    float4 f = *(const float4*)(s + i);
    union { uint2 u; __bf16 h[4]; } p;
    p.h[0] = (__bf16)f.x; p.h[1] = (__bf16)f.y;
    p.h[2] = (__bf16)f.z; p.h[3] = (__bf16)f.w;
    *(uint2*)(d + i) = p.u;
}

// ---------------- fused: convert wq/wk/wv + zero the 8 work-queue counters -----
__global__ __launch_bounds__(256) void cvt3_kernel(const float* __restrict__ wq,
                                                   const float* __restrict__ wk,
                                                   const float* __restrict__ wv,
                                                   __bf16* __restrict__ dq,
                                                   __bf16* __restrict__ dk,
                                                   __bf16* __restrict__ dv,
                                                   int* __restrict__ counters) {
    if (blockIdx.x == 0 && blockIdx.y == 0 && threadIdx.x < 8)
        counters[threadIdx.x] = 0;
    const float* s = blockIdx.y == 0 ? wq : (blockIdx.y == 1 ? wk : wv);
    __bf16*      d = blockIdx.y == 0 ? dq : (blockIdx.y == 1 ? dk : dv);
    int i = (blockIdx.x * 256 + threadIdx.x) * 4;
    float4 f = *(const float4*)(s + i);
    union { uint2 u; __bf16 h[4]; } p;
    p.h[0] = (__bf16)f.x; p.h[1] = (__bf16)f.y;
    p.h[2] = (__bf16)f.z; p.h[3] = (__bf16)f.w;
    *(uint2*)(d + i) = p.u;
}

// ---------------- RMSNorm: fp32 in, bf16 out ----------------
__global__ __launch_bounds__(256) void rmsnorm_kernel(const float* __restrict__ x,
                                                      const float* __restrict__ g,
                                                      __bf16* __restrict__ o) {
    int row = blockIdx.x;
    int t = threadIdx.x;
    float4 xv = ((const float4*)(x + (size_t)row * DIM))[t];
    float ss = xv.x*xv.x + xv.y*xv.y + xv.z*xv.z + xv.w*xv.w;
    #pragma unroll
    for (int off = 32; off; off >>= 1) ss += __shfl_xor(ss, off, 64);
    __shared__ float red[4];
    if ((t & 63) == 0) red[t >> 6] = ss;
    __syncthreads();
    ss = red[0] + red[1] + red[2] + red[3];
    float r = rsqrtf(ss * (1.0f / 1024.0f) + 1.1920929e-07f);
    float4 gv = ((const float4*)g)[t];
    union { uint2 u; __bf16 h[4]; } p;
    p.h[0] = (__bf16)(xv.x * r * gv.x);
    p.h[1] = (__bf16)(xv.y * r * gv.y);
    p.h[2] = (__bf16)(xv.z * r * gv.z);
    p.h[3] = (__bf16)(xv.w * r * gv.w);
    *(uint2*)(o + (size_t)row * DIM + t * 4) = p.u;
}

// ---------------- RoPE in-place on q AND k (4096 x 1024 bf16 each) -------------
__global__ __launch_bounds__(256) void rope_kernel(__bf16* __restrict__ qb,
                                                   __bf16* __restrict__ kb) {
    int bid = blockIdx.x;
    __bf16* x = (bid & 1) ? kb : qb;
    int gid = (bid >> 1) * 256 + threadIdx.x;   // one pair per thread
    int row = gid >> 9;          // 512 pairs per row
    int pr = gid & 511;
    int pos = row & (NSEQ - 1);
    int dp = pr & 31;            // pair index within head
    float inv = __expf(-(float)dp * (9.210340371976184f / 32.0f)); // 10000^(-2dp/64)
    float ang = (float)pos * inv;
    float sn, cs;
    sincosf(ang, &sn, &cs);
    size_t off = (size_t)row * DIM + pr * 2;
    union { unsigned int u; __bf16 h[2]; } p;
    p.u = *(const unsigned int*)(x + off);
    float x1 = (float)p.h[0], x2 = (float)p.h[1];
    p.h[0] = (__bf16)(x1 * cs - x2 * sn);
    p.h[1] = (__bf16)(x2 * cs + x1 * sn);
    *(unsigned int*)(x + off) = p.u;
}

// ---------------- shared GEMM body (unchanged) ----------------
template <typename CT>
__device__ __forceinline__ void gemm_body(const __bf16* __restrict__ A,
                                          const __bf16* __restrict__ B,
                                          CT* __restrict__ C,
                                          int mb, int nb, int ldc, float scale,
                                          __bf16* As, __bf16* Bs) {
    int t = threadIdx.x;
    int w = t >> 6, l = t & 63;
    int wm = (w >> 1) * 64, wn = (w & 1) * 64;   // wave 2x2 grid, each 64x64
    int lrow = l & 15, lq = l >> 4;
    f32x4 acc[4][4] = {};

    int srow = w * 32 + (l >> 3);
    int sc8 = (l & 7) * 8;
    const __bf16* gA = A + (size_t)(mb * 128 + srow) * 1024 + sc8;
    const __bf16* gB = B + (size_t)(nb * 128 + srow) * 1024 + sc8;
    __bf16* lA = As + (size_t)(w * 32) * 64;     // + c*8*64
    __bf16* lB = Bs + (size_t)(w * 32) * 64;

    for (int kt = 0; kt < 16; ++kt) {
        int k0 = kt * 64;
        #pragma unroll
        for (int c = 0; c < 4; ++c) {
            GL2LDS(gA + (size_t)c * 8 * 1024 + k0, lA + c * 8 * 64);
            GL2LDS(gB + (size_t)c * 8 * 1024 + k0, lB + c * 8 * 64);
        }
        __syncthreads();    // drains DMA, publishes tile
        #pragma unroll
        for (int ch = 0; ch < 2; ++ch) {
            bf16x8 af[4], bfr[4];
            #pragma unroll
            for (int i = 0; i < 4; ++i)
                af[i] = *(const bf16x8*)&As[(wm + i * 16 + lrow) * 64 + ch * 32 + lq * 8];
            #pragma unroll
            for (int i = 0; i < 4; ++i)
                bfr[i] = *(const bf16x8*)&Bs[(wn + i * 16 + lrow) * 64 + ch * 32 + lq * 8];
            #pragma unroll
            for (int rt = 0; rt < 4; ++rt)
                #pragma unroll
                for (int ct = 0; ct < 4; ++ct)
                    acc[rt][ct] = MFMA16(af[rt], bfr[ct], acc[rt][ct]);
        }
        __syncthreads();
    }
    #pragma unroll
    for (int rt = 0; rt < 4; ++rt)
        #pragma unroll
        for (int ct = 0; ct < 4; ++ct)
            #pragma unroll
            for (int r = 0; r < 4; ++r) {
                int row = mb * 128 + wm + rt * 16 + lq * 4 + r;   // C-layout
                int col = nb * 128 + wn + ct * 16 + lrow;
                C[(size_t)row * ldc + col] = (CT)(acc[rt][ct][r] * scale);
            }
}

// Fused QKV projections: grid (32, 8, 3) -> 768 blocks = 3 blocks/CU.
// Q scale folds BOTH 1/sqrt(64) AND log2(e): softmax runs in the exp2 domain.
__global__ __launch_bounds__(256) void qkv_kernel(const __bf16* __restrict__ x,
                                                  const __bf16* __restrict__ wq,
                                                  const __bf16* __restrict__ wk,
                                                  const __bf16* __restrict__ wv,
                                                  __bf16* __restrict__ qb,
                                                  __bf16* __restrict__ kb,
                                                  __bf16* __restrict__ vtb) {
    __shared__ __bf16 As[128 * 64];
    __shared__ __bf16 Bs[128 * 64];
    int bm = blockIdx.x, bn = blockIdx.y, z = blockIdx.z;
    if (z == 0)      gemm_body<__bf16>(x,  wq, qb,  bm, bn, 1024,
                                       0.125f * 1.44269504088896340736f, As, Bs);
    else if (z == 1) gemm_body<__bf16>(x,  wk, kb,  bm, bn, 1024, 1.0f,   As, Bs);
    else             gemm_body<__bf16>(wv, x,  vtb, bn, bm, 4096, 1.0f,   As, Bs);
}

// Output projection: all-bf16 DMA path, fp32 store.
__global__ __launch_bounds__(256) void wo_kernel(const __bf16* __restrict__ A,
                                                 const __bf16* __restrict__ B,
                                                 float* __restrict__ C) {
    __shared__ __bf16 As[128 * 64];
    __shared__ __bf16 Bs[128 * 64];
    gemm_body<float>(A, B, C, blockIdx.x, blockIdx.y, 1024, 1.0f, As, Bs);
}

// ---------------- Causal flash attention v5b: split-K wave-pairs + swizzled LDS -
// Same as v5 (R5) with the one correctness fix: a __syncthreads() BEFORE the
// par==1 scratch write in the merge. v5 raced: the last k-loop round has no
// trailing barrier, so idle par-1 waves clobbered Ps[0..1] (the merge scratch
// aliases wave 0/1's P^T strips) while waves 0/1 were still reading them for
// their final PV MFMA -> NaN.
// Structure: item = 64-row q-tile (1024 items, 768 workers, LPT). Block's 4
// waves: waves 0,1 = q-rows 0-31/32-63 x EVEN key-tiles; waves 2,3 = same rows
// x ODD key-tiles. Each wave reads each K/V LDS fragment once for TWO 16-row
// MFMA groups -> LDS read cycles per unit work halved vs R2. Partial (m,l,O)
// merged once per item via LDS (flash combine).
// K/V tiles: stride 64 (no pad) + XOR swizzle (T2): 16B-slot' = slot^(row&7)
// -> staging writes and fragment reads conflict-free. LDS ~50KB -> 3 blocks/CU.
__global__ __launch_bounds__(256, 3) void attn_kernel(const __bf16* __restrict__ q,
                                                      const __bf16* __restrict__ kk,
                                                      const __bf16* __restrict__ vt,
                                                      __bf16* __restrict__ o,
                                                      int* __restrict__ counters) {
    int xcd = blockIdx.x & 7;            // dispatch round-robins over XCDs
    int t = threadIdx.x;
    int w = t >> 6, l = t & 63;
    int lrow = l & 15, lq = l >> 4;
    int rw = (w & 1) * 32;               // wave's q-row offset within the item
    int par = w >> 1;                    // key-tile parity this wave handles
    int row0 = t >> 3;                   // staging row 0..31 (also +32)
    int cb = t & 7;                      // staging 16B col-block 0..7

    __shared__ __bf16 Kt[2][64 * 64];    // [parity][key][d], swizzled
    __shared__ __bf16 Vs[2][64 * 64];    // [parity][d][key], swizzled
    __shared__ __bf16 Ps[4][32 * 72];    // per-wave P^T strip; doubles as merge scratch
    __shared__ int s_item;
    __bf16* pw = Ps[w];

    for (;;) {
        if (t == 0) s_item = atomicAdd(&counters[xcd], 1);
        __syncthreads();                 // broadcast item; fences LDS reuse
        int item = s_item;
        if (item >= 128) break;
        int iq = 31 - (item >> 2);       // 64-row q-tile, long-first (LPT)
        int bh = xcd * 4 + (item & 3);   // 4 (b,h) pairs resident per XCD (L2)
        int h = bh & 15;
        int b = bh >> 4;
        int rowbase = b * NSEQ;

        const __bf16* kbase = kk + (size_t)rowbase * DIM + h * 64;
        const __bf16* vbase = vt + (size_t)(h * 64) * 4096 + b * 2048;

        // Q fragments: 2 groups of 16 qrows (wave covers 32 rows)
        bf16x8 qf[2][2];
        #pragma unroll
        for (int g = 0; g < 2; ++g) {
            const __bf16* qp = q + (size_t)(rowbase + iq * 64 + rw + g * 16 + lrow) * DIM + h * 64;
            qf[g][0] = *(const bf16x8*)(qp + lq * 8);
            qf[g][1] = *(const bf16x8*)(qp + 32 + lq * 8);
        }

        f32x4 oacc[2][4] = {};           // O^T per group: [d-chunk], col = qrow
        float m_r[2] = {-1e30f, -1e30f};
        float l_r[2] = {0.0f, 0.0f};

        const __bf16* kg = kbase + (size_t)row0 * DIM + cb * 8;
        const __bf16* vg = vbase + (size_t)row0 * 4096 + cb * 8;
        int dsw0 = (row0 * 8 + (cb ^ (row0 & 7))) * 8;        // swizzled elem offset
        int dsw1 = ((row0 + 32) * 8 + (cb ^ (row0 & 7))) * 8; // (row0+32)&7 == row0&7

        // prologue: stage tile 0 -> buf0, tile 1 -> buf1 (if it exists)
        uint4 k0a, k0b, v0a, v0b, k1a, k1b, v1a, v1b;
        k0a = *(const uint4*)(kg);
        k0b = *(const uint4*)(kg + (size_t)32 * DIM);
        v0a = *(const uint4*)(vg);
        v0b = *(const uint4*)(vg + (size_t)32 * 4096);
        if (iq >= 1) {
            k1a = *(const uint4*)(kg + (size_t)64 * DIM);
            k1b = *(const uint4*)(kg + (size_t)96 * DIM);
            v1a = *(const uint4*)(vg + 64);
            v1b = *(const uint4*)(vg + (size_t)32 * 4096 + 64);
        }
        *(uint4*)&Kt[0][dsw0] = k0a; *(uint4*)&Kt[0][dsw1] = k0b;
        *(uint4*)&Vs[0][dsw0] = v0a; *(uint4*)&Vs[0][dsw1] = v0b;
        if (iq >= 1) {
            *(uint4*)&Kt[1][dsw0] = k1a; *(uint4*)&Kt[1][dsw1] = k1b;
            *(uint4*)&Vs[1][dsw0] = v1a; *(uint4*)&Vs[1][dsw1] = v1b;
        }
        __syncthreads();

        int R = (iq + 2) >> 1;           // rounds = ceil((iq+1)/2)
        for (int rd = 0; rd < R; ++rd) {
            int jt = 2 * rd + par;       // this wave's key-tile
            bool pf = (rd + 1 < R);      // block-uniform
            if (pf) {                    // prefetch next round's tile pair
                int je = 2 * rd + 2;
                size_t ko = (size_t)je * 64 * DIM;
                k0a = *(const uint4*)(kg + ko);
                k0b = *(const uint4*)(kg + ko + (size_t)32 * DIM);
                v0a = *(const uint4*)(vg + je * 64);
                v0b = *(const uint4*)(vg + (size_t)32 * 4096 + je * 64);
                if (je + 1 <= iq) {
                    k1a = *(const uint4*)(kg + ko + (size_t)64 * DIM);
                    k1b = *(const uint4*)(kg + ko + (size_t)96 * DIM);
                    v1a = *(const uint4*)(vg + je * 64 + 64);
                    v1b = *(const uint4*)(vg + (size_t)32 * 4096 + je * 64 + 64);
                }
            }
            if (jt <= iq) {              // wave-uniform: inactive only in last round
                const __bf16* Kb = Kt[par];
                const __bf16* Vb = Vs[par];
                int sw = lrow & 7;
                // QK^T: K fragment read ONCE, used by both q-row groups
                f32x4 st[2][4];
                #pragma unroll
                for (int ct = 0; ct < 4; ++ct) {
                    int rr = (ct * 16 + lrow) * 8;
                    bf16x8 ka0 = *(const bf16x8*)&Kb[(rr + (lq ^ sw)) * 8];
                    bf16x8 ka1 = *(const bf16x8*)&Kb[(rr + ((4 + lq) ^ sw)) * 8];
                    #pragma unroll
                    for (int g = 0; g < 2; ++g) {
                        f32x4 z = {};
                        z = MFMA16(ka0, qf[g][0], z);
                        z = MFMA16(ka1, qf[g][1], z);
                        st[g][ct] = z;   // key = ct*16+lq*4+r, qrow(local) = lrow
                    }
                }
                if (jt == iq) {          // causal mask on diagonal tile
                    #pragma unroll
                    for (int g = 0; g < 2; ++g) {
                        int qrel = rw + g * 16 + lrow;
                        #pragma unroll
                        for (int ct = 0; ct < 4; ++ct)
                            #pragma unroll
                            for (int r = 0; r < 4; ++r)
                                if (ct * 16 + lq * 4 + r > qrel) st[g][ct][r] = -3.0e38f;
                    }
                }
                // online softmax (exp2 domain) per group
                #pragma unroll
                for (int g = 0; g < 2; ++g) {
                    float m0 = fmaxf(fmaxf(st[g][0][0], st[g][0][1]), fmaxf(st[g][0][2], st[g][0][3]));
                    float m1 = fmaxf(fmaxf(st[g][1][0], st[g][1][1]), fmaxf(st[g][1][2], st[g][1][3]));
                    float m2 = fmaxf(fmaxf(st[g][2][0], st[g][2][1]), fmaxf(st[g][2][2], st[g][2][3]));
                    float m3 = fmaxf(fmaxf(st[g][3][0], st[g][3][1]), fmaxf(st[g][3][2], st[g][3][3]));
                    float mx = fmaxf(fmaxf(m0, m1), fmaxf(m2, m3));
                    mx = fmaxf(mx, __shfl_xor(mx, 16, 64));
                    mx = fmaxf(mx, __shfl_xor(mx, 32, 64));
                    if (!__all(mx - m_r[g] <= 8.0f)) {   // defer-max (T13)
                        float mnew = fmaxf(m_r[g], mx);
                        float alpha = __builtin_amdgcn_exp2f(m_r[g] - mnew);
                        l_r[g] *= alpha;
                        #pragma unroll
                        for (int ct = 0; ct < 4; ++ct)
                            #pragma unroll
                            for (int r = 0; r < 4; ++r) oacc[g][ct][r] *= alpha;
                        m_r[g] = mnew;
                    }
                    float ps = 0.0f;
                    #pragma unroll
                    for (int ct = 0; ct < 4; ++ct)
                        #pragma unroll
                        for (int r = 0; r < 4; ++r) {
                            float p = __builtin_amdgcn_exp2f(st[g][ct][r] - m_r[g]);
                            st[g][ct][r] = p;
                            ps += p;
                        }
                    ps += __shfl_xor(ps, 16, 64);
                    ps += __shfl_xor(ps, 32, 64);
                    l_r[g] += ps;
                }
                // P^T -> per-wave strip (stride 72 = 16B-aligned rows)
                #pragma unroll
                for (int g = 0; g < 2; ++g)
                    #pragma unroll
                    for (int ct = 0; ct < 4; ++ct) {
                        union { uint2 u; __bf16 h4[4]; } pk;
                        #pragma unroll
                        for (int r = 0; r < 4; ++r) pk.h4[r] = (__bf16)st[g][ct][r];
                        *(uint2*)&pw[(g * 16 + lrow) * 72 + ct * 16 + lq * 4] = pk.u;
                    }
                bf16x8 pb[2][2];
                #pragma unroll
                for (int g = 0; g < 2; ++g) {
                    pb[g][0] = *(const bf16x8*)&pw[(g * 16 + lrow) * 72 + lq * 8];
                    pb[g][1] = *(const bf16x8*)&pw[(g * 16 + lrow) * 72 + 32 + lq * 8];
                }
                // O^T += V^T * P^T: V fragment read ONCE, used by both groups
                #pragma unroll
                for (int ct = 0; ct < 4; ++ct) {
                    int rr = (ct * 16 + lrow) * 8;
                    bf16x8 va0 = *(const bf16x8*)&Vb[(rr + (lq ^ sw)) * 8];
                    bf16x8 va1 = *(const bf16x8*)&Vb[(rr + ((4 + lq) ^ sw)) * 8];
                    #pragma unroll
                    for (int g = 0; g < 2; ++g) {
                        oacc[g][ct] = MFMA16(va0, pb[g][0], oacc[g][ct]);
                        oacc[g][ct] = MFMA16(va1, pb[g][1], oacc[g][ct]);
                    }
                }
            }
            if (pf) {                    // publish next round's tiles
                __syncthreads();         // everyone done reading bufs
                *(uint4*)&Kt[0][dsw0] = k0a; *(uint4*)&Kt[0][dsw1] = k0b;
                *(uint4*)&Vs[0][dsw0] = v0a; *(uint4*)&Vs[0][dsw1] = v0b;
                if (2 * rd + 3 <= iq) {
                    *(uint4*)&Kt[1][dsw0] = k1a; *(uint4*)&Kt[1][dsw1] = k1b;
                    *(uint4*)&Vs[1][dsw0] = v1a; *(uint4*)&Vs[1][dsw1] = v1b;
                }
                __syncthreads();
            }
        }

        // ---- merge parity partials (flash combine) + store, via Ps as f32 scratch
        __syncthreads();                 // FIX v5->v5b: par-0 waves must finish
                                         // reading their P strips (scratch aliases
                                         // Ps[0..1]) before par-1 waves overwrite.
        float* sc = (float*)&Ps[0][0];               // 18432 B = 2 x 64 x 36 floats
        float* base = sc + (w & 1) * 2304 + l * 36;
        if (par == 1) {
            #pragma unroll
            for (int g = 0; g < 2; ++g)
                #pragma unroll
                for (int ct = 0; ct < 4; ++ct)
                    *(f32x4*)(base + g * 16 + ct * 4) = oacc[g][ct];
            base[32] = m_r[0]; base[33] = m_r[1];
            base[34] = l_r[0]; base[35] = l_r[1];
        }
        __syncthreads();
        if (par == 0) {
            #pragma unroll
            for (int g = 0; g < 2; ++g) {
                float mb = base[32 + g], lb = base[34 + g];
                float m = fmaxf(m_r[g], mb);
                float a  = __builtin_amdgcn_exp2f(m_r[g] - m);
                float bb = __builtin_amdgcn_exp2f(mb - m);
                float rcp = 1.0f / (a * l_r[g] + bb * lb);
                const size_t orow = (size_t)(rowbase + iq * 64 + rw + g * 16 + lrow) * DIM + h * 64;
                #pragma unroll
                for (int ct = 0; ct < 4; ++ct) {
                    f32x4 ob = *(const f32x4*)(base + g * 16 + ct * 4);
                    union { uint2 u; __bf16 h4[4]; } pk;
                    #pragma unroll
                    for (int r = 0; r < 4; ++r)
                        pk.h4[r] = (__bf16)((a * oacc[g][ct][r] + bb * ob[r]) * rcp);
                    *(uint2*)(o + orow + ct * 16 + lq * 4) = pk.u;
                }
            }
        }
    }
}

extern "C" void kernel_launch(void* const* d_in, const int* in_sizes, int n_in,
                              void* d_out, int out_size, void* d_ws, size_t ws_size,
                              hipStream_t stream) {
    const float* tokens = (const float*)d_in[0];
    const float* gamma  = (const float*)d_in[1];
    const float* wq = (const float*)d_in[2];
    const float* wk = (const float*)d_in[3];
    const float* wv = (const float*)d_in[4];
    const float* wo = (const float*)d_in[5];

    __bf16* ws  = (__bf16*)d_ws;
    __bf16* x   = ws;                           // 4096*1024
    __bf16* qb  = x   + (size_t)4096 * 1024;
    __bf16* kb  = qb  + (size_t)4096 * 1024;
    __bf16* vtb = kb  + (size_t)4096 * 1024;    // V^T: 1024 x 4096
    __bf16* ao  = x;                            // alias: attn out reuses x's buffer
    __bf16* wob = qb;                           // alias: qb dead after attn
    float*  out = (float*)d_out;

    // bf16 Q/K/V weights stashed in d_out (consumed by qkv before wo overwrites);
    // work-queue counters at d_out+8MB (written after qkv, dead before wo's C).
    __bf16* wqb = (__bf16*)d_out;
    __bf16* wkb = wqb + (size_t)1024 * 1024;
    __bf16* wvb = wkb + (size_t)1024 * 1024;
    int* counters = (int*)((char*)d_out + (size_t)8 * 1024 * 1024);

    cvt3_kernel<<<dim3(1024, 3), 256, 0, stream>>>(wq, wk, wv, wqb, wkb, wvb, counters);

    rmsnorm_kernel<<<4096, 256, 0, stream>>>(tokens, gamma, x);

    qkv_kernel<<<dim3(32, 8, 3), 256, 0, stream>>>(x, wqb, wkb, wvb, qb, kb, vtb);

    rope_kernel<<<16384, 256, 0, stream>>>(qb, kb);

    attn_kernel<<<768, 256, 0, stream>>>(qb, kb, vtb, ao, counters);

    cvt_kernel<<<1024, 256, 0, stream>>>(wo, wob);   // qb region is dead now

    wo_kernel<<<dim3(32, 8), 256, 0, stream>>>(ao, wob, out);
}